// Round 6
// baseline (295.433 us; speedup 1.0000x reference)
//
#include <hip/hip_runtime.h>
#include <math.h>

// Problem constants (fixed by the reference)
#define MM 12       // M
#define KK 2        // K
#define DD 512      // D
#define CIN 4096    // C_IN
#define NCLS 8
#define NV 16       // N (videos) == LSTM step count
#define TT 32       // T
// Only LSTM batch row t=31 is ever consumed (rows independent; out uses hs[:, -1, :]).

typedef unsigned long long u64;
typedef __attribute__((ext_vector_type(8))) __bf16 bf16x8;
typedef __attribute__((ext_vector_type(4))) float f32x4;

// ws float offsets
#define PART_F   0            // 4*192*1024 floats
#define POOLED_F 786432       // 16*512
#define TAGA_F   794624       // 256 u32
#define TAGB_F   794880       // 256 u32
#define SLOTC_F  795136       // clean slots: 8 reps * 16*512 u64 = 131072 floats
#define SLOTC_END_BYTES ((size_t)(795136 + 131072) * 4)   // ~3.71 MB
#define PART_KS_STRIDE (192 * 1024)

#define MFMA_BF16(A, B, C) __builtin_amdgcn_mfma_f32_16x16x32_bf16((A), (B), (C), 0, 0, 0)

__global__ __launch_bounds__(256, 1) void k_fused(
    const float* __restrict__ base_out, const float* __restrict__ dist,
    const float* __restrict__ w_a, const float* __restrict__ w_ih,
    const float* __restrict__ w_hh, const float* __restrict__ b_ih,
    const float* __restrict__ b_hh, const float* __restrict__ w_cls,
    const float* __restrict__ b_cls,
    float* __restrict__ part, float* __restrict__ pooled,
    unsigned* __restrict__ tagA, unsigned* __restrict__ tagB,
    u64* __restrict__ slots, float* __restrict__ out)
{
  const int wg = blockIdx.x;   // 0..255
  const int tid = threadIdx.x; // 0..255

  // Static LDS (~138 KB; 1 WG/CU)
  __shared__ __align__(16) unsigned short Ah[16 * 40], Al[16 * 40];
  __shared__ __align__(16) unsigned short Bh[192 * 40], Bl[192 * 40];
  __shared__ __align__(16) float whh_s[16][516];
  __shared__ __align__(16) float wih_s[16][516];
  __shared__ __align__(16) float pooled_s[16][520];  // reused as h-history in classifier
  __shared__ float gx_s[16][20];                     // [n][rl], rl = gate*4 + dl
  __shared__ __align__(16) float h_s2[2][DD];        // double-buffered h
  __shared__ float Asum_s[KK * MM * MM];

  // =========================================================================
  // Phase A: GEMM part[ks][j][o] = w_a[o,:chunk] . base_sel[j,:chunk]
  // bf16x3 MFMA (hi/lo split), tile 16o x 192j per WG, KS=4, 32cc steps.
  // =========================================================================
  {
    const int ks = wg >> 6, ot = wg & 63;
    const int cc0 = ks * 1024;
    const int wave = tid >> 6, lane = tid & 63;
    const int jf0 = wave * 3;

    const int sq = tid & 7;
    const int sr = tid >> 3;
    unsigned boff[6];
#pragma unroll
    for (int rep = 0; rep < 6; ++rep) {
      const int j = sr + 32 * rep;
      const int n = j / 12, m = j - n * 12;
      boff[rep] = (unsigned)(((n * TT + 31) * MM + m) * CIN + cc0 + sq * 4);
    }
    const bool aact = tid < 128;
    unsigned aoff = aact ? (unsigned)((ot * 16 + (tid >> 3)) * CIN + cc0 + sq * 4) : 0u;

    f32x4 acc0 = {0.f, 0.f, 0.f, 0.f}, acc1 = acc0, acc2 = acc0;

    float4 pa, pb[6];
    if (aact) pa = *(const float4*)&w_a[aoff];
#pragma unroll
    for (int rep = 0; rep < 6; ++rep) pb[rep] = *(const float4*)&base_out[boff[rep]];

    for (int st = 0; st < 32; ++st) {
      __syncthreads();
      if (aact) {
        const int idx = (tid >> 3) * 40 + sq * 4;
        unsigned ux = __float_as_uint(pa.x), uy = __float_as_uint(pa.y);
        unsigned uz = __float_as_uint(pa.z), uw = __float_as_uint(pa.w);
        *(uint2*)&Ah[idx] = make_uint2((ux >> 16) | (uy & 0xFFFF0000u),
                                       (uz >> 16) | (uw & 0xFFFF0000u));
        unsigned lx = __float_as_uint(pa.x - __uint_as_float(ux & 0xFFFF0000u));
        unsigned ly = __float_as_uint(pa.y - __uint_as_float(uy & 0xFFFF0000u));
        unsigned lz = __float_as_uint(pa.z - __uint_as_float(uz & 0xFFFF0000u));
        unsigned lw = __float_as_uint(pa.w - __uint_as_float(uw & 0xFFFF0000u));
        *(uint2*)&Al[idx] = make_uint2((lx >> 16) | (ly & 0xFFFF0000u),
                                       (lz >> 16) | (lw & 0xFFFF0000u));
      }
#pragma unroll
      for (int rep = 0; rep < 6; ++rep) {
        const int idx = (sr + 32 * rep) * 40 + sq * 4;
        unsigned ux = __float_as_uint(pb[rep].x), uy = __float_as_uint(pb[rep].y);
        unsigned uz = __float_as_uint(pb[rep].z), uw = __float_as_uint(pb[rep].w);
        *(uint2*)&Bh[idx] = make_uint2((ux >> 16) | (uy & 0xFFFF0000u),
                                       (uz >> 16) | (uw & 0xFFFF0000u));
        unsigned lx = __float_as_uint(pb[rep].x - __uint_as_float(ux & 0xFFFF0000u));
        unsigned ly = __float_as_uint(pb[rep].y - __uint_as_float(uy & 0xFFFF0000u));
        unsigned lz = __float_as_uint(pb[rep].z - __uint_as_float(uz & 0xFFFF0000u));
        unsigned lw = __float_as_uint(pb[rep].w - __uint_as_float(uw & 0xFFFF0000u));
        *(uint2*)&Bl[idx] = make_uint2((lx >> 16) | (ly & 0xFFFF0000u),
                                       (lz >> 16) | (lw & 0xFFFF0000u));
      }
      __syncthreads();
      if (st < 31) {
        aoff += 32;
        if (aact) pa = *(const float4*)&w_a[aoff];
#pragma unroll
        for (int rep = 0; rep < 6; ++rep) {
          boff[rep] += 32;
          pb[rep] = *(const float4*)&base_out[boff[rep]];
        }
      }
      const int koff = (lane >> 4) * 8;
      const int fra = (lane & 15) * 40 + koff;
      bf16x8 oh = *(const bf16x8*)&Ah[fra];
      bf16x8 ol = *(const bf16x8*)&Al[fra];
      {
        const int r0 = ((jf0 + 0) * 16 + (lane & 15)) * 40 + koff;
        bf16x8 jh = *(const bf16x8*)&Bh[r0], jl = *(const bf16x8*)&Bl[r0];
        acc0 = MFMA_BF16(jh, oh, acc0);
        acc0 = MFMA_BF16(jh, ol, acc0);
        acc0 = MFMA_BF16(jl, oh, acc0);
      }
      {
        const int r1 = ((jf0 + 1) * 16 + (lane & 15)) * 40 + koff;
        bf16x8 jh = *(const bf16x8*)&Bh[r1], jl = *(const bf16x8*)&Bl[r1];
        acc1 = MFMA_BF16(jh, oh, acc1);
        acc1 = MFMA_BF16(jh, ol, acc1);
        acc1 = MFMA_BF16(jl, oh, acc1);
      }
      {
        const int r2 = ((jf0 + 2) * 16 + (lane & 15)) * 40 + koff;
        bf16x8 jh = *(const bf16x8*)&Bh[r2], jl = *(const bf16x8*)&Bl[r2];
        acc2 = MFMA_BF16(jh, oh, acc2);
        acc2 = MFMA_BF16(jh, ol, acc2);
        acc2 = MFMA_BF16(jl, oh, acc2);
      }
    }
    // C/D layout: col(o) = lane&15, row(j) = (lane>>4)*4 + reg   [m89-verified]
    const int o = ot * 16 + (lane & 15);
    const int jr = (lane >> 4) * 4;
#pragma unroll
    for (int r = 0; r < 4; ++r) {
      part[((size_t)ks * 192 + (jf0 + 0) * 16 + jr + r) * 1024 + o] = acc0[r];
      part[((size_t)ks * 192 + (jf0 + 1) * 16 + jr + r) * 1024 + o] = acc1[r];
      part[((size_t)ks * 192 + (jf0 + 2) * 16 + jr + r) * 1024 + o] = acc2[r];
    }
    __syncthreads();
    if (tid == 0)
      __hip_atomic_store(&tagA[wg], 1u, __ATOMIC_RELEASE, __HIP_MEMORY_SCOPE_AGENT);
  }

  // Overlap: preload LSTM weights into LDS while fence 1 settles
  if (wg < 128) {
    for (int f = tid; f < 16 * DD; f += 256) {
      const int rl = f >> 9, col = f & 511;
      const int row = (rl >> 2) * DD + wg * 4 + (rl & 3);   // gate*512 + dim
      whh_s[rl][col] = w_hh[(size_t)row * DD + col];
      wih_s[rl][col] = w_ih[(size_t)row * DD + col];
    }
  }

  // ---- fence 1 (all GEMM tiles visible); sleep-backoff spin ----
  while (__hip_atomic_load(&tagA[tid], __ATOMIC_RELAXED, __HIP_MEMORY_SCOPE_AGENT) != 1u)
    __builtin_amdgcn_s_sleep(2);
  __syncthreads();
  (void)__hip_atomic_load(&tagA[0], __ATOMIC_ACQUIRE, __HIP_MEMORY_SCOPE_AGENT);

  // =========================================================================
  // Phase B: pool — WG (n = wg>>4, c-block = (wg&15)*32)
  // =========================================================================
  {
    const int n = wg >> 4, cb = (wg & 15) * 32;
    const unsigned dbase = (unsigned)((n * TT + 31) * (3 * KK * MM * MM));
    for (int f = tid; f < KK * MM * MM; f += 256)
      Asum_s[f] = dist[dbase + f] + dist[dbase + KK * MM * MM + f]
                + dist[dbase + 2 * KK * MM * MM + f];
    __syncthreads();
    if (tid < 32) {
      const int c = cb + tid;
      float nd[KK][MM];
#pragma unroll
      for (int k = 0; k < KK; ++k)
#pragma unroll
        for (int v = 0; v < MM; ++v) {
          const size_t off = (size_t)(n * MM + v) * 1024 + k * DD + c;
          nd[k][v] = part[off] + part[off + PART_KS_STRIDE]
                   + part[off + 2 * PART_KS_STRIDE] + part[off + 3 * PART_KS_STRIDE];
        }
      float accm = 0.f;
#pragma unroll
      for (int w = 0; w < MM; ++w) {
        float sw = 0.f;
#pragma unroll
        for (int k = 0; k < KK; ++k)
#pragma unroll
          for (int v = 0; v < MM; ++v) sw += nd[k][v] * Asum_s[(k * MM + v) * MM + w];
        accm += fmaxf(sw, 0.f);
      }
      pooled[n * DD + c] = accm * (1.f / 12.f);
    }
    __syncthreads();
    if (tid == 0)
      __hip_atomic_store(&tagB[wg], 1u, __ATOMIC_RELEASE, __HIP_MEMORY_SCOPE_AGENT);
  }
  if (wg >= 128) return;   // only 128 WGs run the LSTM

  // ---- fence 2 (pooled visible) ----
  while (__hip_atomic_load(&tagB[tid], __ATOMIC_RELAXED, __HIP_MEMORY_SCOPE_AGENT) != 1u)
    __builtin_amdgcn_s_sleep(2);
  __syncthreads();
  (void)__hip_atomic_load(&tagB[0], __ATOMIC_ACQUIRE, __HIP_MEMORY_SCOPE_AGENT);

  // =========================================================================
  // Phase C: gx in LDS — thread (rl = tid&15, n = tid>>4)
  // =========================================================================
  for (int f = tid; f < NV * DD; f += 256) pooled_s[f >> 9][f & 511] = pooled[f];
  __syncthreads();
  {
    const int rl = tid & 15, n = tid >> 4;
    const float4* wr = (const float4*)&wih_s[rl][0];
    const float4* pv = (const float4*)&pooled_s[n][0];
    float a = 0.f;
#pragma unroll 8
    for (int q = 0; q < DD / 4; ++q) {
      float4 x = wr[q], y = pv[q];
      a += x.x * y.x + x.y * y.y + x.z * y.z + x.w * y.w;
    }
    const int row = (rl >> 2) * DD + wg * 4 + (rl & 3);
    gx_s[n][rl] = a + b_ih[row] + b_hh[row];
  }
  __syncthreads();

  // =========================================================================
  // Phase D: LSTM tagged dataflow. Wave wv owns dim wg*4+wv; its 4 gate-rows
  // (rl = gate*4+wv) are computed by 16-lane groups; gates gathered by
  // intra-wave shfl; lane 0 does activations; lanes 0..7 publish 8 replicas.
  // ONE barrier/step (h double-buffered). Slots are in FRESH memory.
  // =========================================================================
  {
    const int lane = tid & 63;
    const int wv   = tid >> 6;      // wave index == local dim
    const int gate = lane >> 4;     // 0..3
    const int lj   = lane & 15;     // 16-lane slice
    const int rl   = gate * 4 + wv; // whh_s row for (gate, dim wv)
    float c_reg = 0.f;

    for (int s = 0; s < NV; ++s) {
      float* hb = h_s2[s & 1];
      if (s == 0) {
        hb[tid] = 0.f; hb[tid + 256] = 0.f;
      } else {
        const u64* slot = slots + ((size_t)(wg & 7) * NV + (s - 1)) * DD;
        u64 v0 = __hip_atomic_load(&slot[tid], __ATOMIC_RELAXED, __HIP_MEMORY_SCOPE_AGENT);
        while ((unsigned)v0 != (unsigned)s) {
          __builtin_amdgcn_s_sleep(1);
          v0 = __hip_atomic_load(&slot[tid], __ATOMIC_RELAXED, __HIP_MEMORY_SCOPE_AGENT);
        }
        u64 v1 = __hip_atomic_load(&slot[tid + 256], __ATOMIC_RELAXED, __HIP_MEMORY_SCOPE_AGENT);
        while ((unsigned)v1 != (unsigned)s) {
          __builtin_amdgcn_s_sleep(1);
          v1 = __hip_atomic_load(&slot[tid + 256], __ATOMIC_RELAXED, __HIP_MEMORY_SCOPE_AGENT);
        }
        hb[tid] = __uint_as_float((unsigned)(v0 >> 32));
        hb[tid + 256] = __uint_as_float((unsigned)(v1 >> 32));
      }
      __syncthreads();   // staging done; dbuf makes a tail barrier unnecessary

      float p = 0.f;
      const float4* wrow = (const float4*)&whh_s[rl][0];
      const float4* hv4 = (const float4*)hb;
#pragma unroll
      for (int q = 0; q < 8; ++q) {
        float4 wvv = wrow[lj + 16 * q];
        float4 hv = hv4[lj + 16 * q];
        p += wvv.x * hv.x + wvv.y * hv.y + wvv.z * hv.z + wvv.w * hv.w;
      }
#pragma unroll
      for (int off = 8; off; off >>= 1) p += __shfl_down(p, off, 16);
      // lanes 0/16/32/48 hold the 4 gate-dots for dim wg*4+wv
      const float di = __shfl(p, 0, 64);
      const float df = __shfl(p, 16, 64);
      const float dg = __shfl(p, 32, 64);
      const float dq = __shfl(p, 48, 64);
      u64 pk = 0;
      if (lane == 0) {
        const float pi = gx_s[s][wv]      + di;
        const float pf = gx_s[s][4 + wv]  + df;
        const float pg = gx_s[s][8 + wv]  + dg;
        const float po = gx_s[s][12 + wv] + dq;
        const float si = 1.f / (1.f + expf(-pi));
        const float sf = 1.f / (1.f + expf(-pf));
        const float so = 1.f / (1.f + expf(-po));
        c_reg = sf * c_reg + si * tanhf(pg);
        const float hn = so * tanhf(c_reg);
        pk = ((u64)__float_as_uint(hn) << 32) | (u64)(unsigned)(s + 1);
      }
      pk = __shfl(pk, 0, 64);
      if (lane < 8)   // 8 replicas, one store per lane
        __hip_atomic_store(&slots[((size_t)lane * NV + s) * DD + wg * 4 + wv], pk,
                           __ATOMIC_RELAXED, __HIP_MEMORY_SCOPE_AGENT);
    }
  }

  // ---- classifier tail (WG 0): out[n,cl] = h(step n) . w_cls[cl] + b_cls ----
  if (wg == 0) {
    __syncthreads();
    for (int f = tid; f < NV * DD; f += 256) {
      const int ss = f >> 9, d = f & 511;
      u64 v = __hip_atomic_load(&slots[(size_t)ss * DD + d],
                                __ATOMIC_RELAXED, __HIP_MEMORY_SCOPE_AGENT);
      while ((unsigned)v != (unsigned)(ss + 1)) {
        __builtin_amdgcn_s_sleep(1);
        v = __hip_atomic_load(&slots[(size_t)ss * DD + d],
                              __ATOMIC_RELAXED, __HIP_MEMORY_SCOPE_AGENT);
      }
      pooled_s[ss][d] = __uint_as_float((unsigned)(v >> 32));
    }
    __syncthreads();
    if (tid < NV * NCLS) {
      const int n = tid >> 3, cl = tid & 7;
      const float4* hv = (const float4*)&pooled_s[n][0];
      const float4* wv = (const float4*)(w_cls + (size_t)cl * DD);
      float a = b_cls[cl];
#pragma unroll 8
      for (int q = 0; q < DD / 4; ++q) {
        float4 x = hv[q], y = wv[q];
        a += x.x * y.x + x.y * y.y + x.z * y.z + x.w * y.w;
      }
      out[tid] = a;
    }
  }
}

extern "C" void kernel_launch(void* const* d_in, const int* in_sizes, int n_in,
                              void* d_out, int out_size, void* d_ws, size_t ws_size,
                              hipStream_t stream) {
  const float* base_out = (const float*)d_in[0];
  const float* dist     = (const float*)d_in[1];
  const float* w_a      = (const float*)d_in[2];
  const float* w_ih     = (const float*)d_in[3];
  const float* w_hh     = (const float*)d_in[4];
  const float* b_ih     = (const float*)d_in[5];
  const float* b_hh     = (const float*)d_in[6];
  const float* w_cls    = (const float*)d_in[7];
  const float* b_cls    = (const float*)d_in[8];
  float* out = (float*)d_out;

  float* ws = (float*)d_ws;
  float* part   = ws + PART_F;
  float* pooled = ws + POOLED_F;
  unsigned* tagA = (unsigned*)(ws + TAGA_F);
  unsigned* tagB = (unsigned*)(ws + TAGB_F);
  // Clean (non-aliased) slot region if ws allows; else proven R5 aliasing.
  u64* slots = (ws_size >= SLOTC_END_BYTES) ? (u64*)(ws + SLOTC_F) : (u64*)ws;

  // Tags/slots self-validate against the 0xAA re-poison; h_0 generated in-kernel.
  k_fused<<<dim3(256), 256, 0, stream>>>(base_out, dist, w_a, w_ih, w_hh,
                                         b_ih, b_hh, w_cls, b_cls,
                                         part, pooled, tagA, tagB, slots, out);
}